// Round 8
// baseline (589.436 us; speedup 1.0000x reference)
//
#include <hip/hip_runtime.h>
#include <math.h>

#define DIM 64
#define NFEAT 14
#define EFEAT 4
#define ODIM 16
#define NGRAPH 512
#define NEG 0.01f
#define EBLK 256
#define DSPLIT 4

typedef _Float16 f16;
typedef _Float16 f16x8 __attribute__((ext_vector_type(8)));
typedef float f32x4 __attribute__((ext_vector_type(4)));

#define MFMA(a,b,c) __builtin_amdgcn_mfma_f32_16x16x32_f16(a,b,c,0,0,0)

__device__ __forceinline__ float leaky(float v){ return v >= 0.f ? v : NEG*v; }
__device__ __forceinline__ float sigm(float v){ return 1.f/(1.f+expf(-v)); }

// ---------- generic B-fragment packer ----------
// dst fragment layout (consumed as f16x8): flat f16 idx = ((CT*2+s)*64 + l)*8 + j
// value = B[k][c] with k=(l>>4)*8+32*s+j, c=CT*16+(l&15)
// transB=0: B[k][c] = src[c*64+k]   transB=1: B[k][c] = src[k*NC+c]
__global__ void k_pack(const float* __restrict__ src, f16* __restrict__ dst, int NC, int transB){
    int i = blockIdx.x*blockDim.x + threadIdx.x;
    if (i >= NC*64) return;
    int j = i & 7, l = (i >> 3) & 63, s = (i >> 9) & 1, CT = i >> 10;
    int k = ((l >> 4) << 3) + 32*s + j;
    int c = CT*16 + (l & 15);
    float v = transB ? src[(size_t)k*NC + c] : src[(size_t)c*64 + k];
    dst[i] = (f16)v;
}

// ---------- small prep ----------
__global__ void k_hid(const float* __restrict__ ea, const float* __restrict__ w1,
                      const float* __restrict__ b1, f16* __restrict__ hid16, int E){
    int i = blockIdx.x*blockDim.x + threadIdx.x;
    if (i >= E*DIM) return;
    int e = i >> 6, k = i & 63;
    const float* a = ea + (size_t)e*EFEAT;
    const float* w = w1 + k*EFEAT;
    float v = b1[k] + a[0]*w[0] + a[1]*w[1] + a[2]*w[2] + a[3]*w[3];
    hid16[i] = (f16)leaky(v);
}

__global__ void k_deg(const int* __restrict__ ei, float* __restrict__ deg, int E){
    int e = blockIdx.x*blockDim.x + threadIdx.x;
    if (e < E) atomicAdd(&deg[ei[E + e]], 1.0f);
}

__global__ void k_invdeg(float* __restrict__ deg, int N){
    int i = blockIdx.x*blockDim.x + threadIdx.x;
    if (i < N) deg[i] = 1.0f / fmaxf(deg[i], 1.0f);
}

__global__ void k_lin0(const float* __restrict__ x, const float* __restrict__ w,
                       const float* __restrict__ b, float* __restrict__ hf,
                       f16* __restrict__ out16, int N){
    int i = blockIdx.x*blockDim.x + threadIdx.x;
    if (i >= N*DIM) return;
    int n = i >> 6, o = i & 63;
    const float* xr = x + (size_t)n*NFEAT;
    const float* wr = w + o*NFEAT;
    float v = b[o];
#pragma unroll
    for (int f = 0; f < NFEAT; ++f) v += xr[f]*wr[f];
    v = leaky(v);
    hf[i] = v; out16[i] = (f16)v;
}

// ---------- per-node bias GEMM: nb = out16 @ b2  (N x 64) — used once (iter 0) ----------
__global__ __launch_bounds__(256) void k_nbias(const f16x8* __restrict__ out16v,
                                               const f16x8* __restrict__ b2f,
                                               float* __restrict__ nb, int N){
    int n0 = blockIdx.x*64;
    int tid = threadIdx.x, w = tid >> 6, l = tid & 63, li = l & 15, lh = l >> 4;
    int ar = n0 + 16*w + li;
    f16x8 a0{}, a1{};
    if (ar < N){ a0 = out16v[(size_t)ar*8 + lh]; a1 = out16v[(size_t)ar*8 + lh + 4]; }
    f32x4 z = {0.f,0.f,0.f,0.f};
#pragma unroll
    for (int ct = 0; ct < 4; ++ct){
        f32x4 p = MFMA(a0, b2f[(ct*2+0)*64 + l], z);
        p = MFMA(a1, b2f[(ct*2+1)*64 + l], p);
#pragma unroll
        for (int reg = 0; reg < 4; ++reg){
            int n = n0 + 16*w + lh*4 + reg;
            if (n < N) nb[(size_t)n*64 + ct*16 + li] = p[reg];
        }
    }
}

// ---------- fused message: 47KB LDS, 3 blocks/CU, rt=4, single-buffer chunks ----------
__global__ __launch_bounds__(256, 2) void k_fmsg(const float* __restrict__ hf,
                                                 const f16x8* __restrict__ hid16v,
                                                 const f16x8* __restrict__ wpf,
                                                 const float* __restrict__ nb,
                                                 const int* __restrict__ ei,
                                                 float* __restrict__ agg, int E){
    __shared__ f16x8 Wlds[2048];        // 4 d-slices, 32 KB (single buffer)
    __shared__ f16 OsT[EBLK][24];       // 12 KB, row-major, padded
    __shared__ int ssrc[EBLK];
    __shared__ int stgt[EBLK];
    int tid = threadIdx.x;
    int e0 = blockIdx.x*EBLK;
    int dz = blockIdx.y;                // 0..3
    int dbase = dz*16;
    {
        int e = e0 + tid;
        ssrc[tid] = (e < E) ? ei[e] : -1;
        stgt[tid] = (e < E) ? ei[E + e] : -1;
    }
    __syncthreads();
    // OsT[r][dl] = (f16) hf[src_r*64 + dbase + dl], one row per thread
    {
        int s = ssrc[tid];
        float tmpf[16];
#pragma unroll
        for (int j = 0; j < 16; ++j) tmpf[j] = 0.f;
        if (s >= 0){
            const float4* hp = (const float4*)(hf + (size_t)s*64 + dbase);
            *(float4*)&tmpf[0]  = hp[0];
            *(float4*)&tmpf[4]  = hp[1];
            *(float4*)&tmpf[8]  = hp[2];
            *(float4*)&tmpf[12] = hp[3];
        }
        f16 tmph[16];
#pragma unroll
        for (int j = 0; j < 16; ++j) tmph[j] = (f16)tmpf[j];
        *(f16x8*)&OsT[tid][0] = *(f16x8*)&tmph[0];
        *(f16x8*)&OsT[tid][8] = *(f16x8*)&tmph[8];
    }

    int w = tid >> 6, l = tid & 63, li = l & 15, lh = l >> 4;
    // A-fragments: wave w owns rows [w*64, w*64+64)
    f16x8 a[4][2];
#pragma unroll
    for (int rt = 0; rt < 4; ++rt){
        int e = e0 + w*64 + rt*16 + li;
        if (e < E){
            a[rt][0] = hid16v[(size_t)e*8 + lh];
            a[rt][1] = hid16v[(size_t)e*8 + lh + 4];
        } else { a[rt][0] = f16x8{}; a[rt][1] = f16x8{}; }
    }

    f32x4 acc[4][4] = {};

    for (int c = 0; c < 4; ++c){
        __syncthreads();   // protect Wlds readers of previous chunk (and OsT at c=0)
        const f16x8* src = wpf + (size_t)(dbase + c*4)*512;
#pragma unroll
        for (int i = 0; i < 8; ++i) Wlds[tid + i*256] = src[tid + i*256];
        __syncthreads();
#pragma unroll
        for (int dd = 0; dd < 4; ++dd){
            int dl = c*4 + dd;
            f16x8 as[4][2];
#pragma unroll
            for (int rt = 0; rt < 4; ++rt){
                f16 s = OsT[w*64 + rt*16 + li][dl];
                as[rt][0] = a[rt][0]*s;
                as[rt][1] = a[rt][1]*s;
            }
#pragma unroll
            for (int ct = 0; ct < 4; ++ct){
                f16x8 b0 = Wlds[(dd*8 + ct*2 + 0)*64 + l];
                f16x8 b1 = Wlds[(dd*8 + ct*2 + 1)*64 + l];
#pragma unroll
                for (int rt = 0; rt < 4; ++rt){
                    acc[rt][ct] = MFMA(as[rt][0], b0, acc[rt][ct]);
                    acc[rt][ct] = MFMA(as[rt][1], b1, acc[rt][ct]);
                }
            }
        }
    }

    // scatter partials; dz==0 also adds the per-src-node bias term
#pragma unroll
    for (int rt = 0; rt < 4; ++rt){
#pragma unroll
        for (int reg = 0; reg < 4; ++reg){
            int row = w*64 + rt*16 + lh*4 + reg;
            int t = stgt[row];
            if (t < 0) continue;
            int s = ssrc[row];
#pragma unroll
            for (int ct = 0; ct < 4; ++ct){
                int col = ct*16 + li;
                float v = acc[rt][ct][reg];
                if (dz == 0) v += nb[(size_t)s*64 + col];
                atomicAdd(&agg[(size_t)t*64 + col], v);
            }
        }
    }
}

// ---------- conv + GRU node update (MFMA) + agg clear + next-iter nb ----------
__global__ __launch_bounds__(256) void k_node(float* __restrict__ hf,
                                              f16* __restrict__ out16,
                                              const f16x8* __restrict__ out16v,
                                              float* __restrict__ agg,
                                              const float* __restrict__ invdeg,
                                              const float* __restrict__ convb,
                                              const f16x8* __restrict__ wrf,
                                              const f16x8* __restrict__ wihf,
                                              const f16x8* __restrict__ whhf,
                                              const float* __restrict__ bih,
                                              const float* __restrict__ bhh,
                                              const f16x8* __restrict__ b2f,
                                              float* __restrict__ nb, int N){
    __shared__ f16 Ms[64][72];
    int n0 = blockIdx.x*64;
    int tid = threadIdx.x, w = tid >> 6, l = tid & 63, li = l & 15, lh = l >> 4;
    f32x4 z = {0.f,0.f,0.f,0.f};

    int ar = n0 + 16*w + li;
    f16x8 a0{}, a1{};
    if (ar < N){ a0 = out16v[(size_t)ar*8 + lh]; a1 = out16v[(size_t)ar*8 + lh + 4]; }

    int nrow[4]; float invd[4];
#pragma unroll
    for (int reg = 0; reg < 4; ++reg){
        nrow[reg] = n0 + 16*w + lh*4 + reg;
        invd[reg] = (nrow[reg] < N) ? invdeg[nrow[reg]] : 0.f;
    }

    // phase 1: m = leaky(agg*invdeg + out@rootw + convb); clear agg for next iter
#pragma unroll
    for (int ct = 0; ct < 4; ++ct){
        f32x4 p = MFMA(a0, wrf[(ct*2+0)*64 + l], z);
        p = MFMA(a1, wrf[(ct*2+1)*64 + l], p);
        int col = ct*16 + li;
        float cb = convb[col];
#pragma unroll
        for (int reg = 0; reg < 4; ++reg){
            int n = nrow[reg];
            float m = 0.f;
            if (n < N){
                size_t idx = (size_t)n*64 + col;
                m = leaky(p[reg] + agg[idx]*invd[reg] + cb);
                agg[idx] = 0.f;
            }
            Ms[16*w + lh*4 + reg][col] = (f16)m;
        }
    }
    __syncthreads();

    // phase 2: GRU gates
    f16x8 am0 = *(const f16x8*)&Ms[16*w + li][lh*8];
    f16x8 am1 = *(const f16x8*)&Ms[16*w + li][lh*8 + 32];

#pragma unroll
    for (int ctq = 0; ctq < 4; ++ctq){
        int col = ctq*16 + li;
        f32x4 pir = MFMA(am0, wihf[((ctq+0)*2+0)*64 + l], z);
        pir = MFMA(am1, wihf[((ctq+0)*2+1)*64 + l], pir);
        f32x4 piz = MFMA(am0, wihf[((ctq+4)*2+0)*64 + l], z);
        piz = MFMA(am1, wihf[((ctq+4)*2+1)*64 + l], piz);
        f32x4 pin = MFMA(am0, wihf[((ctq+8)*2+0)*64 + l], z);
        pin = MFMA(am1, wihf[((ctq+8)*2+1)*64 + l], pin);
        f32x4 phr = MFMA(a0, whhf[((ctq+0)*2+0)*64 + l], z);
        phr = MFMA(a1, whhf[((ctq+0)*2+1)*64 + l], phr);
        f32x4 phz = MFMA(a0, whhf[((ctq+4)*2+0)*64 + l], z);
        phz = MFMA(a1, whhf[((ctq+4)*2+1)*64 + l], phz);
        f32x4 phn = MFMA(a0, whhf[((ctq+8)*2+0)*64 + l], z);
        phn = MFMA(a1, whhf[((ctq+8)*2+1)*64 + l], phn);
        float bir = bih[col], biz = bih[64+col], bin = bih[128+col];
        float bhr = bhh[col], bhz = bhh[64+col], bhn = bhh[128+col];
        __syncthreads();   // Ms reads of phase 2 done; safe to overwrite below
#pragma unroll
        for (int reg = 0; reg < 4; ++reg){
            int n = nrow[reg];
            float hnew = 0.f;
            if (n < N){
                float hv = hf[(size_t)n*64 + col];
                float r  = sigm(pir[reg] + bir + phr[reg] + bhr);
                float zz = sigm(piz[reg] + biz + phz[reg] + bhz);
                float nn = tanhf(pin[reg] + bin + r*(phn[reg] + bhn));
                hnew = (1.f - zz)*nn + zz*hv;
                hf[(size_t)n*64 + col] = hnew;
                out16[(size_t)n*64 + col] = (f16)hnew;
            }
            Ms[16*w + lh*4 + reg][col] = (f16)hnew;
        }
    }
    __syncthreads();

    // phase 3: nb = out_new @ b2
    f16x8 an0 = *(const f16x8*)&Ms[16*w + li][lh*8];
    f16x8 an1 = *(const f16x8*)&Ms[16*w + li][lh*8 + 32];
#pragma unroll
    for (int ct = 0; ct < 4; ++ct){
        f32x4 p = MFMA(an0, b2f[(ct*2+0)*64 + l], z);
        p = MFMA(an1, b2f[(ct*2+1)*64 + l], p);
#pragma unroll
        for (int reg = 0; reg < 4; ++reg){
            int n = nrow[reg];
            if (n < N) nb[(size_t)n*64 + ct*16 + li] = p[reg];
        }
    }
}

// ---------- Set2Set (1 step, zero init) + readout ----------
__global__ void k_q(const float* __restrict__ bih, const float* __restrict__ bhh,
                    float* __restrict__ q){
    int j = threadIdx.x;
    if (j >= 64) return;
    float gi = bih[j]       + bhh[j];
    float gg = bih[128+j]   + bhh[128+j];
    float go = bih[192+j]   + bhh[192+j];
    float c = sigm(gi)*tanhf(gg);
    q[j] = sigm(go)*tanhf(c);
}

__device__ __forceinline__ unsigned fkey(float f){
    unsigned u = __float_as_uint(f);
    return (u >> 31) ? ~u : (u | 0x80000000u);
}

__global__ void k_edot(const float* __restrict__ out, const float* __restrict__ q,
                       const int* __restrict__ batch, float* __restrict__ ebuf,
                       unsigned* __restrict__ emaxk, int N){
    int gw = (blockIdx.x*blockDim.x + threadIdx.x) >> 6;
    int d = threadIdx.x & 63;
    if (gw >= N) return;
    float v = out[(size_t)gw*64 + d] * q[d];
#pragma unroll
    for (int s = 32; s; s >>= 1) v += __shfl_xor(v, s, 64);
    if (d == 0){
        ebuf[gw] = v;
        atomicMax(&emaxk[batch[gw]], fkey(v));
    }
}

__global__ void k_ex(float* __restrict__ ebuf, const unsigned* __restrict__ emaxk,
                     const int* __restrict__ batch, float* __restrict__ denom, int N){
    int n = blockIdx.x*blockDim.x + threadIdx.x;
    if (n >= N) return;
    int b = batch[n];
    unsigned k = emaxk[b];
    float em = (k == 0u) ? 0.f
             : ((k >> 31) ? __uint_as_float(k ^ 0x80000000u) : __uint_as_float(~k));
    float ex = expf(ebuf[n] - em);
    ebuf[n] = ex;
    atomicAdd(&denom[b], ex);
}

__global__ void k_rr(const float* __restrict__ out, const float* __restrict__ ebuf,
                     const float* __restrict__ denom, const int* __restrict__ batch,
                     float* __restrict__ rr, int N){
    int gw = (blockIdx.x*blockDim.x + threadIdx.x) >> 6;
    int o = threadIdx.x & 63;
    if (gw >= N) return;
    int b = batch[gw];
    float a = ebuf[gw] / fmaxf(denom[b], 1e-16f);
    atomicAdd(&rr[(size_t)b*64 + o], a * out[(size_t)gw*64 + o]);
}

__global__ void k_out(const float* __restrict__ q, const float* __restrict__ rr,
                      const float* __restrict__ lw, const float* __restrict__ lb,
                      float* __restrict__ dout){
    int i = blockIdx.x*blockDim.x + threadIdx.x;
    if (i >= NGRAPH*ODIM) return;
    int b = i / ODIM, j = i % ODIM;
    const float* w = lw + j*128;
    float acc = lb[j];
#pragma unroll 8
    for (int d = 0; d < 64; ++d) acc += w[d]*q[d];
    const float* rb = rr + (size_t)b*64;
#pragma unroll 8
    for (int d = 0; d < 64; ++d) acc += w[64+d]*rb[d];
    dout[i] = acc;
}

// ---------- launch ----------
extern "C" void kernel_launch(void* const* d_in, const int* in_sizes, int n_in,
                              void* d_out, int out_size, void* d_ws, size_t ws_size,
                              hipStream_t stream){
    const float* x     = (const float*)d_in[0];
    const float* ea    = (const float*)d_in[1];
    const int*   ei    = (const int*)  d_in[2];
    const int*   batch = (const int*)  d_in[3];
    const float* lin0w = (const float*)d_in[4];
    const float* lin0b = (const float*)d_in[5];
    const float* w1    = (const float*)d_in[6];
    const float* b1    = (const float*)d_in[7];
    const float* w2    = (const float*)d_in[8];
    const float* b2    = (const float*)d_in[9];
    const float* rootw = (const float*)d_in[10];
    const float* convb = (const float*)d_in[11];
    const float* gwih  = (const float*)d_in[12];
    const float* gwhh  = (const float*)d_in[13];
    const float* gbih  = (const float*)d_in[14];
    const float* gbhh  = (const float*)d_in[15];
    const float* lsbih = (const float*)d_in[18];
    const float* lsbhh = (const float*)d_in[19];
    const float* loutw = (const float*)d_in[20];
    const float* loutb = (const float*)d_in[21];

    int N = in_sizes[0] / NFEAT;
    int E = in_sizes[1] / EFEAT;

    char* p = (char*)d_ws;
    size_t off = 0;
    auto carve = [&](size_t bytes) -> void* {
        void* r = p + off;
        off += (bytes + 255) & ~(size_t)255;
        return r;
    };
    f16*      hid16  = (f16*)     carve((size_t)E*64*2);
    float*    hf     = (float*)   carve((size_t)N*64*4);
    f16*      out16  = (f16*)     carve((size_t)N*64*2);
    float*    nb     = (float*)   carve((size_t)N*64*4);
    float*    qv     = (float*)   carve(64*4);
    float*    ebuf   = (float*)   carve((size_t)N*4);
    f16*      wpf    = (f16*)     carve((size_t)4096*64*2);
    f16*      wrf    = (f16*)     carve(64*64*2);
    f16*      b2f    = (f16*)     carve(64*64*2);
    f16*      wihf   = (f16*)     carve(192*64*2);
    f16*      whhf   = (f16*)     carve(192*64*2);
    // ---- contiguous zeroed region (single memset) ----
    size_t zero_beg = off;
    float*    agg    = (float*)   carve((size_t)N*64*4);
    float*    invdeg = (float*)   carve((size_t)N*4);
    unsigned* emaxk  = (unsigned*)carve(NGRAPH*4);
    float*    denom  = (float*)   carve(NGRAPH*4);
    float*    rr     = (float*)   carve((size_t)NGRAPH*64*4);
    size_t zero_end = off;

    hipMemsetAsync(p + zero_beg, 0, zero_end - zero_beg, stream);

    k_pack<<<(4096*64 + 255)/256, 256, 0, stream>>>(w2,    wpf,  4096, 0);
    k_pack<<<(64*64   + 255)/256, 256, 0, stream>>>(rootw, wrf,  64,   1);
    k_pack<<<(64*64   + 255)/256, 256, 0, stream>>>(b2,    b2f,  64,   1);
    k_pack<<<(192*64  + 255)/256, 256, 0, stream>>>(gwih,  wihf, 192,  0);
    k_pack<<<(192*64  + 255)/256, 256, 0, stream>>>(gwhh,  whhf, 192,  0);

    k_hid<<<((size_t)E*64 + 255)/256, 256, 0, stream>>>(ea, w1, b1, hid16, E);
    k_deg<<<(E + 255)/256, 256, 0, stream>>>(ei, invdeg, E);
    k_invdeg<<<(N + 255)/256, 256, 0, stream>>>(invdeg, N);
    k_lin0<<<((size_t)N*64 + 255)/256, 256, 0, stream>>>(x, lin0w, lin0b, hf, out16, N);

    int eb  = (E + EBLK - 1)/EBLK;
    int nbk = (N + 63)/64;
    int node_grid = ((size_t)N*64 + 255)/256;

    k_nbias<<<nbk, 256, 0, stream>>>((const f16x8*)out16, (const f16x8*)b2f, nb, N);
    for (int it = 0; it < 6; ++it){
        k_fmsg<<<dim3(eb, DSPLIT), 256, 0, stream>>>(hf, (const f16x8*)hid16,
                                                     (const f16x8*)wpf, nb, ei, agg, E);
        k_node<<<nbk, 256, 0, stream>>>(hf, out16, (const f16x8*)out16, agg, invdeg,
                                        convb, (const f16x8*)wrf, (const f16x8*)wihf,
                                        (const f16x8*)whhf, gbih, gbhh,
                                        (const f16x8*)b2f, nb, N);
    }

    k_q<<<1, 64, 0, stream>>>(lsbih, lsbhh, qv);
    k_edot<<<node_grid, 256, 0, stream>>>(hf, qv, batch, ebuf, emaxk, N);
    k_ex<<<(N + 255)/256, 256, 0, stream>>>(ebuf, emaxk, batch, denom, N);
    k_rr<<<node_grid, 256, 0, stream>>>(hf, ebuf, denom, batch, rr, N);
    k_out<<<(NGRAPH*ODIM + 255)/256, 256, 0, stream>>>(qv, rr, loutw, loutb, (float*)d_out);
}

// Round 9
// 496.772 us; speedup vs baseline: 1.1865x; 1.1865x over previous
//
#include <hip/hip_runtime.h>
#include <math.h>

#define DIM 64
#define NFEAT 14
#define EFEAT 4
#define ODIM 16
#define NGRAPH 512
#define NEG 0.01f
#define EBLK 128
#define DSPLIT 2

typedef _Float16 f16;
typedef _Float16 f16x8 __attribute__((ext_vector_type(8)));
typedef float f32x4 __attribute__((ext_vector_type(4)));

#define MFMA(a,b,c) __builtin_amdgcn_mfma_f32_16x16x32_f16(a,b,c,0,0,0)

__device__ __forceinline__ float leaky(float v){ return v >= 0.f ? v : NEG*v; }
__device__ __forceinline__ float sigm(float v){ return 1.f/(1.f+expf(-v)); }

// ---------- generic B-fragment packer ----------
// dst fragment layout (consumed as f16x8): flat f16 idx = ((CT*2+s)*64 + l)*8 + j
// value = B[k][c] with k=(l>>4)*8+32*s+j, c=CT*16+(l&15)
// transB=0: B[k][c] = src[c*64+k]   transB=1: B[k][c] = src[k*NC+c]
__global__ void k_pack(const float* __restrict__ src, f16* __restrict__ dst, int NC, int transB){
    int i = blockIdx.x*blockDim.x + threadIdx.x;
    if (i >= NC*64) return;
    int j = i & 7, l = (i >> 3) & 63, s = (i >> 9) & 1, CT = i >> 10;
    int k = ((l >> 4) << 3) + 32*s + j;
    int c = CT*16 + (l & 15);
    float v = transB ? src[(size_t)k*NC + c] : src[(size_t)c*64 + k];
    dst[i] = (f16)v;
}

// ---------- small prep ----------
__global__ void k_hid(const float* __restrict__ ea, const float* __restrict__ w1,
                      const float* __restrict__ b1, f16* __restrict__ hid16, int E){
    int i = blockIdx.x*blockDim.x + threadIdx.x;
    if (i >= E*DIM) return;
    int e = i >> 6, k = i & 63;
    const float* a = ea + (size_t)e*EFEAT;
    const float* w = w1 + k*EFEAT;
    float v = b1[k] + a[0]*w[0] + a[1]*w[1] + a[2]*w[2] + a[3]*w[3];
    hid16[i] = (f16)leaky(v);
}

__global__ void k_deg(const int* __restrict__ ei, float* __restrict__ deg, int E){
    int e = blockIdx.x*blockDim.x + threadIdx.x;
    if (e < E) atomicAdd(&deg[ei[E + e]], 1.0f);
}

__global__ void k_invdeg(float* __restrict__ deg, int N){
    int i = blockIdx.x*blockDim.x + threadIdx.x;
    if (i < N) deg[i] = 1.0f / fmaxf(deg[i], 1.0f);
}

__global__ void k_lin0(const float* __restrict__ x, const float* __restrict__ w,
                       const float* __restrict__ b, float* __restrict__ hf,
                       f16* __restrict__ out16, int N){
    int i = blockIdx.x*blockDim.x + threadIdx.x;
    if (i >= N*DIM) return;
    int n = i >> 6, o = i & 63;
    const float* xr = x + (size_t)n*NFEAT;
    const float* wr = w + o*NFEAT;
    float v = b[o];
#pragma unroll
    for (int f = 0; f < NFEAT; ++f) v += xr[f]*wr[f];
    v = leaky(v);
    hf[i] = v; out16[i] = (f16)v;
}

// ---------- per-node bias GEMM: nb = out16 @ b2  (N x 64) — used once (iter 0) ----------
__global__ __launch_bounds__(256) void k_nbias(const f16x8* __restrict__ out16v,
                                               const f16x8* __restrict__ b2f,
                                               float* __restrict__ nb, int N){
    int n0 = blockIdx.x*64;
    int tid = threadIdx.x, w = tid >> 6, l = tid & 63, li = l & 15, lh = l >> 4;
    int ar = n0 + 16*w + li;
    f16x8 a0{}, a1{};
    if (ar < N){ a0 = out16v[(size_t)ar*8 + lh]; a1 = out16v[(size_t)ar*8 + lh + 4]; }
    f32x4 z = {0.f,0.f,0.f,0.f};
#pragma unroll
    for (int ct = 0; ct < 4; ++ct){
        f32x4 p = MFMA(a0, b2f[(ct*2+0)*64 + l], z);
        p = MFMA(a1, b2f[(ct*2+1)*64 + l], p);
#pragma unroll
        for (int reg = 0; reg < 4; ++reg){
            int n = n0 + 16*w + lh*4 + reg;
            if (n < N) nb[(size_t)n*64 + ct*16 + li] = p[reg];
        }
    }
}

// ---------- fused message: 42KB LDS / 3 blocks/CU, issue-early prefetch, dz=2 ----------
__global__ __launch_bounds__(256) void k_fmsg(const float* __restrict__ hf,
                                              const f16x8* __restrict__ hid16v,
                                              const f16x8* __restrict__ wpf,
                                              const float* __restrict__ nb,
                                              const int* __restrict__ ei,
                                              float* __restrict__ agg, int E){
    __shared__ f16x8 Wlds[2048];        // 4 d-slices, 32 KB
    __shared__ f16 OsT[EBLK][36];       // 9.2 KB
    __shared__ int ssrc[EBLK];
    __shared__ int stgt[EBLK];
    int tid = threadIdx.x;
    int e0 = blockIdx.x*EBLK;
    int dbase = blockIdx.y*32;          // dz in {0,1}
    if (tid < EBLK){
        int e = e0 + tid;
        ssrc[tid] = (e < E) ? ei[e] : -1;
        stgt[tid] = (e < E) ? ei[E + e] : -1;
    }
    __syncthreads();
    // OsT[r][dl] = (f16) hf[src_r*64 + dbase + dl]
    for (int i = tid; i < EBLK*32; i += 256){
        int r = i >> 5, dl = i & 31;
        int s = ssrc[r];
        OsT[r][dl] = (s >= 0) ? (f16)hf[(size_t)s*64 + dbase + dl] : (f16)0.f;
    }

    int w = tid >> 6, l = tid & 63, li = l & 15, lh = l >> 4;
    // A-fragments: wave w owns rows [w*32, w*32+32)
    f16x8 a[2][2];
#pragma unroll
    for (int rt = 0; rt < 2; ++rt){
        int e = e0 + w*32 + rt*16 + li;
        if (e < E){
            a[rt][0] = hid16v[(size_t)e*8 + lh];
            a[rt][1] = hid16v[(size_t)e*8 + lh + 4];
        } else { a[rt][0] = f16x8{}; a[rt][1] = f16x8{}; }
    }

    // prologue: prefetch chunk 0 into regs
    f16x8 p[8];
    {
        const f16x8* src = wpf + (size_t)dbase*512;
#pragma unroll
        for (int i = 0; i < 8; ++i) p[i] = src[tid + i*256];
    }

    f32x4 acc[2][4] = {};

    for (int c = 0; c < 8; ++c){
        __syncthreads();                 // previous chunk fully consumed
#pragma unroll
        for (int i = 0; i < 8; ++i) Wlds[tid + i*256] = p[i];
        __syncthreads();
        if (c < 7){                      // issue next-chunk loads; they fly during compute
            const f16x8* src = wpf + (size_t)(dbase + (c+1)*4)*512;
#pragma unroll
            for (int i = 0; i < 8; ++i) p[i] = src[tid + i*256];
        }
#pragma unroll
        for (int dd = 0; dd < 4; ++dd){
            int dl = c*4 + dd;
            f16 s0 = OsT[w*32 + li][dl];
            f16 s1 = OsT[w*32 + 16 + li][dl];
            f16x8 as00 = a[0][0]*s0, as01 = a[0][1]*s0;
            f16x8 as10 = a[1][0]*s1, as11 = a[1][1]*s1;
#pragma unroll
            for (int ct = 0; ct < 4; ++ct){
                f16x8 b0 = Wlds[(dd*8 + ct*2 + 0)*64 + l];
                f16x8 b1 = Wlds[(dd*8 + ct*2 + 1)*64 + l];
                acc[0][ct] = MFMA(as00, b0, acc[0][ct]);
                acc[0][ct] = MFMA(as01, b1, acc[0][ct]);
                acc[1][ct] = MFMA(as10, b0, acc[1][ct]);
                acc[1][ct] = MFMA(as11, b1, acc[1][ct]);
            }
        }
    }

    // scatter partials; dz==0 also adds the per-src-node bias term
#pragma unroll
    for (int rt = 0; rt < 2; ++rt){
#pragma unroll
        for (int reg = 0; reg < 4; ++reg){
            int row = w*32 + rt*16 + lh*4 + reg;
            int t = stgt[row];
            if (t < 0) continue;
            int s = ssrc[row];
#pragma unroll
            for (int ct = 0; ct < 4; ++ct){
                int col = ct*16 + li;
                float v = acc[rt][ct][reg];
                if (blockIdx.y == 0) v += nb[(size_t)s*64 + col];
                atomicAdd(&agg[(size_t)t*64 + col], v);
            }
        }
    }
}

// ---------- conv + GRU node update (MFMA), barrier-free (all LDS wave-local) ----------
__global__ __launch_bounds__(256) void k_node(float* __restrict__ hf,
                                              f16* __restrict__ out16,
                                              const f16x8* __restrict__ out16v,
                                              float* __restrict__ agg,
                                              const float* __restrict__ invdeg,
                                              const float* __restrict__ convb,
                                              const f16x8* __restrict__ wrf,
                                              const f16x8* __restrict__ wihf,
                                              const f16x8* __restrict__ whhf,
                                              const float* __restrict__ bih,
                                              const float* __restrict__ bhh,
                                              const f16x8* __restrict__ b2f,
                                              float* __restrict__ nb, int N){
    __shared__ f16 Ms[64][72];          // wave w touches only rows [16w,16w+16)
    int n0 = blockIdx.x*64;
    int tid = threadIdx.x, w = tid >> 6, l = tid & 63, li = l & 15, lh = l >> 4;
    f32x4 z = {0.f,0.f,0.f,0.f};

    int ar = n0 + 16*w + li;
    f16x8 a0{}, a1{};
    if (ar < N){ a0 = out16v[(size_t)ar*8 + lh]; a1 = out16v[(size_t)ar*8 + lh + 4]; }

    int nrow[4]; float invd[4];
#pragma unroll
    for (int reg = 0; reg < 4; ++reg){
        nrow[reg] = n0 + 16*w + lh*4 + reg;
        invd[reg] = (nrow[reg] < N) ? invdeg[nrow[reg]] : 0.f;
    }

    // phase 1: m = leaky(agg*invdeg + out@rootw + convb); clear agg for next iter
#pragma unroll
    for (int ct = 0; ct < 4; ++ct){
        f32x4 p = MFMA(a0, wrf[(ct*2+0)*64 + l], z);
        p = MFMA(a1, wrf[(ct*2+1)*64 + l], p);
        int col = ct*16 + li;
        float cb = convb[col];
#pragma unroll
        for (int reg = 0; reg < 4; ++reg){
            int n = nrow[reg];
            float m = 0.f;
            if (n < N){
                size_t idx = (size_t)n*64 + col;
                m = leaky(p[reg] + agg[idx]*invd[reg] + cb);
                agg[idx] = 0.f;
            }
            Ms[16*w + lh*4 + reg][col] = (f16)m;
        }
    }

    // phase 2: GRU gates (Ms rows are this wave's own; DS ops FIFO per wave)
    f16x8 am0 = *(const f16x8*)&Ms[16*w + li][lh*8];
    f16x8 am1 = *(const f16x8*)&Ms[16*w + li][lh*8 + 32];

#pragma unroll
    for (int ctq = 0; ctq < 4; ++ctq){
        int col = ctq*16 + li;
        f32x4 pir = MFMA(am0, wihf[((ctq+0)*2+0)*64 + l], z);
        pir = MFMA(am1, wihf[((ctq+0)*2+1)*64 + l], pir);
        f32x4 piz = MFMA(am0, wihf[((ctq+4)*2+0)*64 + l], z);
        piz = MFMA(am1, wihf[((ctq+4)*2+1)*64 + l], piz);
        f32x4 pin = MFMA(am0, wihf[((ctq+8)*2+0)*64 + l], z);
        pin = MFMA(am1, wihf[((ctq+8)*2+1)*64 + l], pin);
        f32x4 phr = MFMA(a0, whhf[((ctq+0)*2+0)*64 + l], z);
        phr = MFMA(a1, whhf[((ctq+0)*2+1)*64 + l], phr);
        f32x4 phz = MFMA(a0, whhf[((ctq+4)*2+0)*64 + l], z);
        phz = MFMA(a1, whhf[((ctq+4)*2+1)*64 + l], phz);
        f32x4 phn = MFMA(a0, whhf[((ctq+8)*2+0)*64 + l], z);
        phn = MFMA(a1, whhf[((ctq+8)*2+1)*64 + l], phn);
        float bir = bih[col], biz = bih[64+col], bin = bih[128+col];
        float bhr = bhh[col], bhz = bhh[64+col], bhn = bhh[128+col];
#pragma unroll
        for (int reg = 0; reg < 4; ++reg){
            int n = nrow[reg];
            float hnew = 0.f;
            if (n < N){
                float hv = hf[(size_t)n*64 + col];
                float r  = sigm(pir[reg] + bir + phr[reg] + bhr);
                float zz = sigm(piz[reg] + biz + phz[reg] + bhz);
                float nn = tanhf(pin[reg] + bin + r*(phn[reg] + bhn));
                hnew = (1.f - zz)*nn + zz*hv;
                hf[(size_t)n*64 + col] = hnew;
                out16[(size_t)n*64 + col] = (f16)hnew;
            }
            Ms[16*w + lh*4 + reg][col] = (f16)hnew;
        }
    }

    // phase 3: nb = out_new @ b2
    f16x8 an0 = *(const f16x8*)&Ms[16*w + li][lh*8];
    f16x8 an1 = *(const f16x8*)&Ms[16*w + li][lh*8 + 32];
#pragma unroll
    for (int ct = 0; ct < 4; ++ct){
        f32x4 p = MFMA(an0, b2f[(ct*2+0)*64 + l], z);
        p = MFMA(an1, b2f[(ct*2+1)*64 + l], p);
#pragma unroll
        for (int reg = 0; reg < 4; ++reg){
            int n = nrow[reg];
            if (n < N) nb[(size_t)n*64 + ct*16 + li] = p[reg];
        }
    }
}

// ---------- Set2Set (1 step, zero init) + readout ----------
__global__ void k_q(const float* __restrict__ bih, const float* __restrict__ bhh,
                    float* __restrict__ q){
    int j = threadIdx.x;
    if (j >= 64) return;
    float gi = bih[j]       + bhh[j];
    float gg = bih[128+j]   + bhh[128+j];
    float go = bih[192+j]   + bhh[192+j];
    float c = sigm(gi)*tanhf(gg);
    q[j] = sigm(go)*tanhf(c);
}

__device__ __forceinline__ unsigned fkey(float f){
    unsigned u = __float_as_uint(f);
    return (u >> 31) ? ~u : (u | 0x80000000u);
}

__global__ void k_edot(const float* __restrict__ out, const float* __restrict__ q,
                       const int* __restrict__ batch, float* __restrict__ ebuf,
                       unsigned* __restrict__ emaxk, int N){
    int gw = (blockIdx.x*blockDim.x + threadIdx.x) >> 6;
    int d = threadIdx.x & 63;
    if (gw >= N) return;
    float v = out[(size_t)gw*64 + d] * q[d];
#pragma unroll
    for (int s = 32; s; s >>= 1) v += __shfl_xor(v, s, 64);
    if (d == 0){
        ebuf[gw] = v;
        atomicMax(&emaxk[batch[gw]], fkey(v));
    }
}

__global__ void k_ex(float* __restrict__ ebuf, const unsigned* __restrict__ emaxk,
                     const int* __restrict__ batch, float* __restrict__ denom, int N){
    int n = blockIdx.x*blockDim.x + threadIdx.x;
    if (n >= N) return;
    int b = batch[n];
    unsigned k = emaxk[b];
    float em = (k == 0u) ? 0.f
             : ((k >> 31) ? __uint_as_float(k ^ 0x80000000u) : __uint_as_float(~k));
    float ex = expf(ebuf[n] - em);
    ebuf[n] = ex;
    atomicAdd(&denom[b], ex);
}

__global__ void k_rr(const float* __restrict__ out, const float* __restrict__ ebuf,
                     const float* __restrict__ denom, const int* __restrict__ batch,
                     float* __restrict__ rr, int N){
    int gw = (blockIdx.x*blockDim.x + threadIdx.x) >> 6;
    int o = threadIdx.x & 63;
    if (gw >= N) return;
    int b = batch[gw];
    float a = ebuf[gw] / fmaxf(denom[b], 1e-16f);
    atomicAdd(&rr[(size_t)b*64 + o], a * out[(size_t)gw*64 + o]);
}

__global__ void k_out(const float* __restrict__ q, const float* __restrict__ rr,
                      const float* __restrict__ lw, const float* __restrict__ lb,
                      float* __restrict__ dout){
    int i = blockIdx.x*blockDim.x + threadIdx.x;
    if (i >= NGRAPH*ODIM) return;
    int b = i / ODIM, j = i % ODIM;
    const float* w = lw + j*128;
    float acc = lb[j];
#pragma unroll 8
    for (int d = 0; d < 64; ++d) acc += w[d]*q[d];
    const float* rb = rr + (size_t)b*64;
#pragma unroll 8
    for (int d = 0; d < 64; ++d) acc += w[64+d]*rb[d];
    dout[i] = acc;
}

// ---------- launch ----------
extern "C" void kernel_launch(void* const* d_in, const int* in_sizes, int n_in,
                              void* d_out, int out_size, void* d_ws, size_t ws_size,
                              hipStream_t stream){
    const float* x     = (const float*)d_in[0];
    const float* ea    = (const float*)d_in[1];
    const int*   ei    = (const int*)  d_in[2];
    const int*   batch = (const int*)  d_in[3];
    const float* lin0w = (const float*)d_in[4];
    const float* lin0b = (const float*)d_in[5];
    const float* w1    = (const float*)d_in[6];
    const float* b1    = (const float*)d_in[7];
    const float* w2    = (const float*)d_in[8];
    const float* b2    = (const float*)d_in[9];
    const float* rootw = (const float*)d_in[10];
    const float* convb = (const float*)d_in[11];
    const float* gwih  = (const float*)d_in[12];
    const float* gwhh  = (const float*)d_in[13];
    const float* gbih  = (const float*)d_in[14];
    const float* gbhh  = (const float*)d_in[15];
    const float* lsbih = (const float*)d_in[18];
    const float* lsbhh = (const float*)d_in[19];
    const float* loutw = (const float*)d_in[20];
    const float* loutb = (const float*)d_in[21];

    int N = in_sizes[0] / NFEAT;
    int E = in_sizes[1] / EFEAT;

    char* p = (char*)d_ws;
    size_t off = 0;
    auto carve = [&](size_t bytes) -> void* {
        void* r = p + off;
        off += (bytes + 255) & ~(size_t)255;
        return r;
    };
    f16*      hid16  = (f16*)     carve((size_t)E*64*2);
    float*    hf     = (float*)   carve((size_t)N*64*4);
    f16*      out16  = (f16*)     carve((size_t)N*64*2);
    float*    nb     = (float*)   carve((size_t)N*64*4);
    float*    qv     = (float*)   carve(64*4);
    float*    ebuf   = (float*)   carve((size_t)N*4);
    f16*      wpf    = (f16*)     carve((size_t)4096*64*2);
    f16*      wrf    = (f16*)     carve(64*64*2);
    f16*      b2f    = (f16*)     carve(64*64*2);
    f16*      wihf   = (f16*)     carve(192*64*2);
    f16*      whhf   = (f16*)     carve(192*64*2);
    // ---- contiguous zeroed region (single memset) ----
    size_t zero_beg = off;
    float*    agg    = (float*)   carve((size_t)N*64*4);
    float*    invdeg = (float*)   carve((size_t)N*4);
    unsigned* emaxk  = (unsigned*)carve(NGRAPH*4);
    float*    denom  = (float*)   carve(NGRAPH*4);
    float*    rr     = (float*)   carve((size_t)NGRAPH*64*4);
    size_t zero_end = off;

    hipMemsetAsync(p + zero_beg, 0, zero_end - zero_beg, stream);

    k_pack<<<(4096*64 + 255)/256, 256, 0, stream>>>(w2,    wpf,  4096, 0);
    k_pack<<<(64*64   + 255)/256, 256, 0, stream>>>(rootw, wrf,  64,   1);
    k_pack<<<(64*64   + 255)/256, 256, 0, stream>>>(b2,    b2f,  64,   1);
    k_pack<<<(192*64  + 255)/256, 256, 0, stream>>>(gwih,  wihf, 192,  0);
    k_pack<<<(192*64  + 255)/256, 256, 0, stream>>>(gwhh,  whhf, 192,  0);

    k_hid<<<((size_t)E*64 + 255)/256, 256, 0, stream>>>(ea, w1, b1, hid16, E);
    k_deg<<<(E + 255)/256, 256, 0, stream>>>(ei, invdeg, E);
    k_invdeg<<<(N + 255)/256, 256, 0, stream>>>(invdeg, N);
    k_lin0<<<((size_t)N*64 + 255)/256, 256, 0, stream>>>(x, lin0w, lin0b, hf, out16, N);

    int eb  = (E + EBLK - 1)/EBLK;
    int nbk = (N + 63)/64;
    int node_grid = ((size_t)N*64 + 255)/256;

    k_nbias<<<nbk, 256, 0, stream>>>((const f16x8*)out16, (const f16x8*)b2f, nb, N);
    for (int it = 0; it < 6; ++it){
        k_fmsg<<<dim3(eb, DSPLIT), 256, 0, stream>>>(hf, (const f16x8*)hid16,
                                                     (const f16x8*)wpf, nb, ei, agg, E);
        k_node<<<nbk, 256, 0, stream>>>(hf, out16, (const f16x8*)out16, agg, invdeg,
                                        convb, (const f16x8*)wrf, (const f16x8*)wihf,
                                        (const f16x8*)whhf, gbih, gbhh,
                                        (const f16x8*)b2f, nb, N);
    }

    k_q<<<1, 64, 0, stream>>>(lsbih, lsbhh, qv);
    k_edot<<<node_grid, 256, 0, stream>>>(hf, qv, batch, ebuf, emaxk, N);
    k_ex<<<(N + 255)/256, 256, 0, stream>>>(ebuf, emaxk, batch, denom, N);
    k_rr<<<node_grid, 256, 0, stream>>>(hf, ebuf, denom, batch, rr, N);
    k_out<<<(NGRAPH*ODIM + 255)/256, 256, 0, stream>>>(qv, rr, loutw, loutb, (float*)d_out);
}